// Round 11
// baseline (168.803 us; speedup 1.0000x reference)
//
#include <hip/hip_runtime.h>
#include <hip/hip_bf16.h>

// Problem constants (reference: B,S,E,H,DK = 2,1024,1024,128,8)
#define Bv  2
#define Sv  1024
#define Ev  1024
#define Hv  128
#define DKv 8
#define Mv  (Bv*Sv)

// softmax scale folding: c = log2(e)/sqrt(8) = 0.5100697
// om *= SQC (=sqrt(c)) at GEMM1 epilogue; Wo *= ISQC at cvt; SQC*ISQC == 1
#define SQC  0.7141916f
#define ISQC 1.4001855f

typedef __attribute__((ext_vector_type(8))) short short8;
typedef __attribute__((ext_vector_type(4))) float f32x4;

static __device__ __forceinline__ short f2b(float f) {
    __hip_bfloat16 h = __float2bfloat16(f);
    return *reinterpret_cast<short*>(&h);
}

// packed f32x2 -> bf16x2 (low = a, high = b), RNE
static __device__ __forceinline__ unsigned cvtpk(float a, float b) {
    unsigned r;
    asm("v_cvt_pk_bf16_f32 %0, %1, %2" : "=v"(r) : "v"(a), "v"(b));
    return r;
}

// hardware exp2 (v_exp_f32)
static __device__ __forceinline__ float hexp2(float x) {
    return __builtin_amdgcn_exp2f(x);
}

// async global->LDS, 16B per lane; LDS dest = wave-uniform base + lane*16
static __device__ __forceinline__ void gload16(const void* g, void* l) {
    __builtin_amdgcn_global_load_lds(
        (const __attribute__((address_space(1))) unsigned int*)g,
        (__attribute__((address_space(3))) unsigned int*)l, 16, 0, 0);
}

// ---------------------------------------------------------------------------
// fused fp32 -> bf16 cast: x (1024 blk), Wq (512 blk), Wo*ISQC (512 blk)
// ---------------------------------------------------------------------------
__global__ __launch_bounds__(256)
void cvt_all(const float* __restrict__ x, const float* __restrict__ wq,
             const float* __restrict__ wo, short* __restrict__ xb,
             short* __restrict__ wqb, short* __restrict__ wob)
{
    const int b = blockIdx.x;
    const float* src; short* dst; int i; float sc = 1.0f;
    if (b < 1024)      { src = x;  dst = xb;  i = b * 256 + threadIdx.x; }
    else if (b < 1536) { src = wq; dst = wqb; i = (b - 1024) * 256 + threadIdx.x; }
    else               { src = wo; dst = wob; i = (b - 1536) * 256 + threadIdx.x; sc = ISQC; }
    float4 a = ((const float4*)src)[2 * i];
    float4 c = ((const float4*)src)[2 * i + 1];
    uint4 o;
    o.x = cvtpk(a.x * sc, a.y * sc); o.y = cvtpk(a.z * sc, a.w * sc);
    o.z = cvtpk(c.x * sc, c.y * sc); o.w = cvtpk(c.z * sc, c.w * sc);
    ((uint4*)dst)[i] = o;
}

// ---------------------------------------------------------------------------
// bf16 MFMA GEMM (NT), r8/r10-verified: BM=BN=64, BK=64, 512 blocks (2/CU),
// 4 waves, dbuf LDS (one barrier/K-step), gload16 with pre-swizzled source
// col; read slot = (kk/8+g)^(fragrow&7). Bijective XCD swizzle on 1D grid.
// EPI==0: om = bf16 cos(acc+bq+phi)*SQC scattered to [B,H,S,DK]
// EPI==1: out = fp32 acc + bo, row-major [M,E]
// ---------------------------------------------------------------------------
template<int EPI>
__global__ __launch_bounds__(256)
void gemm_bf16(const short* __restrict__ A, const short* __restrict__ W,
               const float* __restrict__ bias, const float* __restrict__ phi,
               void* __restrict__ outv)
{
    __shared__ short As[2][64 * 64];   // 8 KB each
    __shared__ short Bs[2][64 * 64];

    const int t    = threadIdx.x;
    const int w    = t >> 6, lane = t & 63;
    const int c    = lane & 15, g = lane >> 4;
    const int cs   = c & 7;
    const int wr   = w >> 1,  wc = w & 1;
    const int bid  = blockIdx.x;
    const int swz  = (bid & 7) * 64 + (bid >> 3);   // XCD-aware, bijective (512%8==0)
    const int tn   = (swz & 15) * 64, tm = (swz >> 4) * 64;
    const int lr   = lane >> 3;                    // row in 8-row group
    const int lcs  = ((lane & 7) ^ lr) * 8;        // pre-swizzled source col

    f32x4 acc[2][2] = {};

    #define STAGE(s, k0)                                                        \
        _Pragma("unroll")                                                       \
        for (int j = 0; j < 2; j++) {                                           \
            const int row = w * 16 + j * 8;                                     \
            gload16(&A[(size_t)(tm + row + lr) * Ev + (k0) + lcs], &As[s][row * 64]); \
            gload16(&W[(size_t)(tn + row + lr) * Ev + (k0) + lcs], &Bs[s][row * 64]); \
        }

    STAGE(0, 0)
    __syncthreads();

    for (int ks = 0; ks < 16; ks++) {
        const int cur = ks & 1;
        if (ks < 15) { STAGE(cur ^ 1, (ks + 1) * 64) }
        #pragma unroll
        for (int kk = 0; kk < 64; kk += 32) {
            const int s0 = ((kk >> 3) + g) ^ cs;   // swizzled read slot
            short8 af[2], bf[2];
            #pragma unroll
            for (int m = 0; m < 2; m++)
                af[m] = *(const short8*)&As[cur][(wr * 32 + m * 16 + c) * 64 + s0 * 8];
            #pragma unroll
            for (int n = 0; n < 2; n++)
                bf[n] = *(const short8*)&Bs[cur][(wc * 32 + n * 16 + c) * 64 + s0 * 8];
            #pragma unroll
            for (int m = 0; m < 2; m++)
                #pragma unroll
                for (int n = 0; n < 2; n++)
                    acc[m][n] = __builtin_amdgcn_mfma_f32_16x16x32_bf16(af[m], bf[n], acc[m][n], 0, 0, 0);
        }
        __syncthreads();
    }

    // epilogue: D layout row = 4*(lane>>4)+reg, col = lane&15
    #pragma unroll
    for (int i = 0; i < 2; i++) {
        #pragma unroll
        for (int j = 0; j < 2; j++) {
            const int n = tn + wc * 32 + j * 16 + c;
            #pragma unroll
            for (int r = 0; r < 4; r++) {
                const int m = tm + wr * 32 + i * 16 + 4 * g + r;
                const float v = acc[i][j][r];
                if (EPI == 0) {
                    float q = __cosf(v + bias[n] + phi[n]) * SQC;
                    const int bb = m >> 10, ss = m & (Sv - 1);
                    const int hh = n >> 3,  dd = n & (DKv - 1);
                    ((short*)outv)[(((size_t)bb * Hv + hh) * Sv + ss) * DKv + dd] = f2b(q);
                } else {
                    ((float*)outv)[(size_t)m * Ev + n] = v + bias[n];
                }
            }
        }
    }
    #undef STAGE
}

// ---------------------------------------------------------------------------
// MFMA flash attention (r10-verified skeleton). Swapped-QK^T, no max pass
// (om pre-scaled by sqrt(c): exp2 arg <= 4.08, p <= 17 bf16-safe).
// Zero-page pointers for masked lanes; L via ones-column inside PV MFMA.
// NEW vs r10: K-loop hand-unrolled x2 with TWO static P buffers (pb=0/1)
// + #pragma unroll 2 outer -> 4 independent 32-key chains in flight; the
// compiler can run half-B's QK-MFMA/exp under half-A's P write->read wait.
// ---------------------------------------------------------------------------
__global__ __launch_bounds__(256)
void attn_mfma(const short* __restrict__ om, short* __restrict__ ctx)
{
    __shared__ short K_lds[Sv * DKv];        // [k][d]        16 KB
    __shared__ short Vt[DKv * 1032];         // [d][k] padded 16.5 KB
    __shared__ short P_lds[4][2][16][40];    // wave x pbuf x q x keypad, 10 KB
    __shared__ __align__(16) short zpage[8]; // 16B zeros
    __shared__ __align__(16) short opage[8]; // 16B bf16 1.0

    const int t  = threadIdx.x;
    const int bh = blockIdx.x;
    const short* base = om + (size_t)bh * (Sv * DKv);

    if (t < 8) zpage[t] = 0;
    else if (t < 16) opage[t - 8] = 0x3F80;   // bf16 1.0

    #pragma unroll
    for (int r = 0; r < 4; r++) {
        const int k = r * 256 + t;
        int4 row = ((const int4*)base)[k];
        ((int4*)K_lds)[k] = row;
        union { int4 v; short s[8]; } u; u.v = row;
        #pragma unroll
        for (int d = 0; d < 8; d++) Vt[d * 1032 + k] = u.s[d];
    }
    __syncthreads();

    const int w = t >> 6, lane = t & 63;
    const int c = lane & 15, g = lane >> 4;
    const int q0 = blockIdx.y * 64 + w * 16;

    // Q as B-operand: B[k][q=c] = Q[q][k], k<8 valid (g==0 lanes)
    short8 qf = {};
    if (g == 0) qf = *(const short8*)&K_lds[(q0 + c) * 8];

    // per-lane walking pointers; masked lanes pinned to zero/ones pages
    const short* kp0 = (g == 0) ? &K_lds[c * 8]        : zpage;
    const short* kp1 = (g == 0) ? &K_lds[(16 + c) * 8] : zpage;
    const int   kadv = (g == 0) ? 32 * 8 : 0;
    const short* vp  = (c < 8) ? &Vt[c * 1032 + 8 * g] : (c == 8 ? opage : zpage);
    const int   vadv = (c < 8) ? 32 : 0;

    f32x4 acc = {0.f, 0.f, 0.f, 0.f};
    const f32x4 z = {0.f, 0.f, 0.f, 0.f};

    #pragma unroll 2
    for (int kt = 0; kt < Sv; kt += 64) {
        // ---- keys kt .. kt+31  (P buffer 0)
        {
            short8 kf0 = *(const short8*)kp0;  kp0 += kadv;
            short8 kf1 = *(const short8*)kp1;  kp1 += kadv;
            f32x4 s0 = __builtin_amdgcn_mfma_f32_16x16x32_bf16(kf0, qf, z, 0, 0, 0);
            f32x4 s1 = __builtin_amdgcn_mfma_f32_16x16x32_bf16(kf1, qf, z, 0, 0, 0);
            uint2 w0, w1;
            w0.x = cvtpk(hexp2(s0[0]), hexp2(s0[1]));
            w0.y = cvtpk(hexp2(s0[2]), hexp2(s0[3]));
            w1.x = cvtpk(hexp2(s1[0]), hexp2(s1[1]));
            w1.y = cvtpk(hexp2(s1[2]), hexp2(s1[3]));
            *(uint2*)&P_lds[w][0][c][4 * g]      = w0;
            *(uint2*)&P_lds[w][0][c][16 + 4 * g] = w1;
            short8 pf = *(const short8*)&P_lds[w][0][c][8 * g];
            short8 vf = *(const short8*)vp;  vp += vadv;
            acc = __builtin_amdgcn_mfma_f32_16x16x32_bf16(pf, vf, acc, 0, 0, 0);
        }
        // ---- keys kt+32 .. kt+63  (P buffer 1)
        {
            short8 kf0 = *(const short8*)kp0;  kp0 += kadv;
            short8 kf1 = *(const short8*)kp1;  kp1 += kadv;
            f32x4 s0 = __builtin_amdgcn_mfma_f32_16x16x32_bf16(kf0, qf, z, 0, 0, 0);
            f32x4 s1 = __builtin_amdgcn_mfma_f32_16x16x32_bf16(kf1, qf, z, 0, 0, 0);
            uint2 w0, w1;
            w0.x = cvtpk(hexp2(s0[0]), hexp2(s0[1]));
            w0.y = cvtpk(hexp2(s0[2]), hexp2(s0[3]));
            w1.x = cvtpk(hexp2(s1[0]), hexp2(s1[1]));
            w1.y = cvtpk(hexp2(s1[2]), hexp2(s1[3]));
            *(uint2*)&P_lds[w][1][c][4 * g]      = w0;
            *(uint2*)&P_lds[w][1][c][16 + 4 * g] = w1;
            short8 pf = *(const short8*)&P_lds[w][1][c][8 * g];
            short8 vf = *(const short8*)vp;  vp += vadv;
            acc = __builtin_amdgcn_mfma_f32_16x16x32_bf16(pf, vf, acc, 0, 0, 0);
        }
    }

    // L for rows 4g+r lives in lane (c==8, same g), reg r
    float L[4];
    #pragma unroll
    for (int r = 0; r < 4; r++) L[r] = __shfl(acc[r], (lane & 48) | 8);

    if (c < 8) {
        const int b = bh >> 7, h = bh & (Hv - 1);
        #pragma unroll
        for (int r = 0; r < 4; r++) {
            const int q = q0 + 4 * g + r;
            ctx[((size_t)(b * Sv + q)) * Ev + h * DKv + c] = f2b(acc[r] / L[r]);
        }
    }
}

// ---------------------------------------------------------------------------
extern "C" void kernel_launch(void* const* d_in, const int* in_sizes, int n_in,
                              void* d_out, int out_size, void* d_ws, size_t ws_size,
                              hipStream_t stream)
{
    const float* x   = (const float*)d_in[0];
    const float* Wq  = (const float*)d_in[1];
    const float* bq  = (const float*)d_in[2];
    // d_in[3..6] = Wk, bk, Wv, bv -- dead in the reference math.
    const float* phi = (const float*)d_in[7];
    const float* Wo  = (const float*)d_in[8];
    const float* bo  = (const float*)d_in[9];
    float* out = (float*)d_out;

    char* ws = (char*)d_ws;
    short* xb  = (short*)ws;                       // [M,E] bf16, 4 MB
    short* ctx = xb;                               // alias: written after xb's last read
    short* om  = (short*)(ws + (4 << 20));         // [B,H,S,DK] bf16 (*SQC), 4 MB
    short* Wqb = (short*)(ws + (8 << 20));         // [E,E] bf16, 2 MB
    short* Wob = (short*)(ws + (10 << 20));        // [E,E] bf16 (*ISQC), 2 MB

    cvt_all<<<dim3(2048), 256, 0, stream>>>(x, Wq, Wo, xb, Wqb, Wob);

    gemm_bf16<0><<<dim3(512), 256, 0, stream>>>(xb, Wqb, bq, phi, (void*)om);
    attn_mfma<<<dim3(Bv * Hv, Sv / 64), 256, 0, stream>>>(om, ctx);
    gemm_bf16<1><<<dim3(512), 256, 0, stream>>>(ctx, Wob, bo, nullptr, (void*)out);
}

// Round 12
// 159.888 us; speedup vs baseline: 1.0558x; 1.0558x over previous
//
#include <hip/hip_runtime.h>
#include <hip/hip_bf16.h>

// Problem constants (reference: B,S,E,H,DK = 2,1024,1024,128,8)
#define Bv  2
#define Sv  1024
#define Ev  1024
#define Hv  128
#define DKv 8
#define Mv  (Bv*Sv)

// softmax scale folding: c = log2(e)/sqrt(8) = 0.5100697
// om *= SQC (=sqrt(c)) at GEMM1 epilogue; Wo *= ISQC at cvt; SQC*ISQC == 1
#define SQC  0.7141916f
#define ISQC 1.4001855f

typedef __attribute__((ext_vector_type(8))) short short8;
typedef __attribute__((ext_vector_type(4))) float f32x4;

static __device__ __forceinline__ short f2b(float f) {
    __hip_bfloat16 h = __float2bfloat16(f);
    return *reinterpret_cast<short*>(&h);
}

// packed f32x2 -> bf16x2 (low = a, high = b), RNE
static __device__ __forceinline__ unsigned cvtpk(float a, float b) {
    unsigned r;
    asm("v_cvt_pk_bf16_f32 %0, %1, %2" : "=v"(r) : "v"(a), "v"(b));
    return r;
}

// hardware exp2 (v_exp_f32)
static __device__ __forceinline__ float hexp2(float x) {
    return __builtin_amdgcn_exp2f(x);
}

// async global->LDS, 16B per lane; LDS dest = wave-uniform base + lane*16
static __device__ __forceinline__ void gload16(const void* g, void* l) {
    __builtin_amdgcn_global_load_lds(
        (const __attribute__((address_space(1))) unsigned int*)g,
        (__attribute__((address_space(3))) unsigned int*)l, 16, 0, 0);
}

// ---------------------------------------------------------------------------
// fused fp32 -> bf16 cast: x (1024 blk), Wq (512 blk), Wo*ISQC (512 blk)
// ---------------------------------------------------------------------------
__global__ __launch_bounds__(256)
void cvt_all(const float* __restrict__ x, const float* __restrict__ wq,
             const float* __restrict__ wo, short* __restrict__ xb,
             short* __restrict__ wqb, short* __restrict__ wob)
{
    const int b = blockIdx.x;
    const float* src; short* dst; int i; float sc = 1.0f;
    if (b < 1024)      { src = x;  dst = xb;  i = b * 256 + threadIdx.x; }
    else if (b < 1536) { src = wq; dst = wqb; i = (b - 1024) * 256 + threadIdx.x; }
    else               { src = wo; dst = wob; i = (b - 1536) * 256 + threadIdx.x; sc = ISQC; }
    float4 a = ((const float4*)src)[2 * i];
    float4 c = ((const float4*)src)[2 * i + 1];
    uint4 o;
    o.x = cvtpk(a.x * sc, a.y * sc); o.y = cvtpk(a.z * sc, a.w * sc);
    o.z = cvtpk(c.x * sc, c.y * sc); o.w = cvtpk(c.z * sc, c.w * sc);
    ((uint4*)dst)[i] = o;
}

// ---------------------------------------------------------------------------
// bf16 MFMA GEMM (NT), r8/r10-verified fragment/swizzle layout.
// BM=BN=64, BK=64, 512 blocks (2/CU), 4 waves.
// NEW (T3+T4): 3-deep circular LDS buffer + counted vmcnt. Per K-step:
//   issue STAGE(ks+2) -> ds_read+MFMA on buf[ks%3] -> sched_barrier(0)
//   -> s_waitcnt vmcnt(4) lgkmcnt(0) -> raw s_barrier.
// vmcnt(4): each wave has 4 loads/stage in flight for (ks+2); waiting to 4
// drains (ks+1)'s -> next tile ready, prefetch stays in flight ACROSS the
// barrier (never vmcnt(0) in steady state). Buffer (ks+2)%3 == (ks-1)%3:
// its readers all passed the (ks-1) barrier. lgkmcnt(0)+sched_barrier(0)
// pin this iteration's ds_reads before the barrier (rule 18).
// EPI==0: om = bf16 cos(acc+bq+phi)*SQC scattered to [B,H,S,DK]
// EPI==1: out = fp32 acc + bo, row-major [M,E]
// ---------------------------------------------------------------------------
template<int EPI>
__global__ __launch_bounds__(256)
void gemm_bf16(const short* __restrict__ A, const short* __restrict__ W,
               const float* __restrict__ bias, const float* __restrict__ phi,
               void* __restrict__ outv)
{
    __shared__ short As[3][64 * 64];   // 8 KB each, 48 KB total
    __shared__ short Bs[3][64 * 64];

    const int t    = threadIdx.x;
    const int w    = t >> 6, lane = t & 63;
    const int c    = lane & 15, g = lane >> 4;
    const int cs   = c & 7;
    const int wr   = w >> 1,  wc = w & 1;
    const int bid  = blockIdx.x;
    const int swz  = (bid & 7) * 64 + (bid >> 3);   // XCD-aware, bijective (512%8==0)
    const int tn   = (swz & 15) * 64, tm = (swz >> 4) * 64;
    const int lr   = lane >> 3;                    // row in 8-row group
    const int lcs  = ((lane & 7) ^ lr) * 8;        // pre-swizzled source col

    f32x4 acc[2][2] = {};

    #define STAGE(s, k0)                                                        \
        _Pragma("unroll")                                                       \
        for (int j = 0; j < 2; j++) {                                           \
            const int row = w * 16 + j * 8;                                     \
            gload16(&A[(size_t)(tm + row + lr) * Ev + (k0) + lcs], &As[s][row * 64]); \
            gload16(&W[(size_t)(tn + row + lr) * Ev + (k0) + lcs], &Bs[s][row * 64]); \
        }

    STAGE(0, 0)
    STAGE(1, 64)
    asm volatile("s_waitcnt vmcnt(4)" ::: "memory");   // tile0 ready, tile1 in flight
    __builtin_amdgcn_s_barrier();

    #pragma unroll
    for (int ks = 0; ks < 16; ks++) {
        const int cur = ks % 3;
        if (ks + 2 < 16) { STAGE((ks + 2) % 3, (ks + 2) * 64) }

        #pragma unroll
        for (int kk = 0; kk < 64; kk += 32) {
            const int s0 = ((kk >> 3) + g) ^ cs;   // swizzled read slot
            short8 af[2], bf[2];
            #pragma unroll
            for (int m = 0; m < 2; m++)
                af[m] = *(const short8*)&As[cur][(wr * 32 + m * 16 + c) * 64 + s0 * 8];
            #pragma unroll
            for (int n = 0; n < 2; n++)
                bf[n] = *(const short8*)&Bs[cur][(wc * 32 + n * 16 + c) * 64 + s0 * 8];
            #pragma unroll
            for (int m = 0; m < 2; m++)
                #pragma unroll
                for (int n = 0; n < 2; n++)
                    acc[m][n] = __builtin_amdgcn_mfma_f32_16x16x32_bf16(af[m], bf[n], acc[m][n], 0, 0, 0);
        }

        if (ks < 15) {
            __builtin_amdgcn_sched_barrier(0);
            if (ks < 14) asm volatile("s_waitcnt vmcnt(4) lgkmcnt(0)" ::: "memory");
            else         asm volatile("s_waitcnt vmcnt(0) lgkmcnt(0)" ::: "memory");
            __builtin_amdgcn_s_barrier();
        }
    }

    // epilogue: D layout row = 4*(lane>>4)+reg, col = lane&15
    #pragma unroll
    for (int i = 0; i < 2; i++) {
        #pragma unroll
        for (int j = 0; j < 2; j++) {
            const int n = tn + wc * 32 + j * 16 + c;
            #pragma unroll
            for (int r = 0; r < 4; r++) {
                const int m = tm + wr * 32 + i * 16 + 4 * g + r;
                const float v = acc[i][j][r];
                if (EPI == 0) {
                    float q = __cosf(v + bias[n] + phi[n]) * SQC;
                    const int bb = m >> 10, ss = m & (Sv - 1);
                    const int hh = n >> 3,  dd = n & (DKv - 1);
                    ((short*)outv)[(((size_t)bb * Hv + hh) * Sv + ss) * DKv + dd] = f2b(q);
                } else {
                    ((float*)outv)[(size_t)m * Ev + n] = v + bias[n];
                }
            }
        }
    }
    #undef STAGE
}

// ---------------------------------------------------------------------------
// MFMA flash attention (r11 verbatim, verified). Swapped-QK^T, no max pass
// (om pre-scaled by sqrt(c): exp2 arg <= 4.08, p <= 17 bf16-safe).
// Zero-page pointers for masked lanes; L via ones-column inside PV MFMA.
// K-loop unrolled x2 with two static P buffers.
// ---------------------------------------------------------------------------
__global__ __launch_bounds__(256)
void attn_mfma(const short* __restrict__ om, short* __restrict__ ctx)
{
    __shared__ short K_lds[Sv * DKv];        // [k][d]        16 KB
    __shared__ short Vt[DKv * 1032];         // [d][k] padded 16.5 KB
    __shared__ short P_lds[4][2][16][40];    // wave x pbuf x q x keypad, 10 KB
    __shared__ __align__(16) short zpage[8]; // 16B zeros
    __shared__ __align__(16) short opage[8]; // 16B bf16 1.0

    const int t  = threadIdx.x;
    const int bh = blockIdx.x;
    const short* base = om + (size_t)bh * (Sv * DKv);

    if (t < 8) zpage[t] = 0;
    else if (t < 16) opage[t - 8] = 0x3F80;   // bf16 1.0

    #pragma unroll
    for (int r = 0; r < 4; r++) {
        const int k = r * 256 + t;
        int4 row = ((const int4*)base)[k];
        ((int4*)K_lds)[k] = row;
        union { int4 v; short s[8]; } u; u.v = row;
        #pragma unroll
        for (int d = 0; d < 8; d++) Vt[d * 1032 + k] = u.s[d];
    }
    __syncthreads();

    const int w = t >> 6, lane = t & 63;
    const int c = lane & 15, g = lane >> 4;
    const int q0 = blockIdx.y * 64 + w * 16;

    // Q as B-operand: B[k][q=c] = Q[q][k], k<8 valid (g==0 lanes)
    short8 qf = {};
    if (g == 0) qf = *(const short8*)&K_lds[(q0 + c) * 8];

    // per-lane walking pointers; masked lanes pinned to zero/ones pages
    const short* kp0 = (g == 0) ? &K_lds[c * 8]        : zpage;
    const short* kp1 = (g == 0) ? &K_lds[(16 + c) * 8] : zpage;
    const int   kadv = (g == 0) ? 32 * 8 : 0;
    const short* vp  = (c < 8) ? &Vt[c * 1032 + 8 * g] : (c == 8 ? opage : zpage);
    const int   vadv = (c < 8) ? 32 : 0;

    f32x4 acc = {0.f, 0.f, 0.f, 0.f};
    const f32x4 z = {0.f, 0.f, 0.f, 0.f};

    #pragma unroll 2
    for (int kt = 0; kt < Sv; kt += 64) {
        // ---- keys kt .. kt+31  (P buffer 0)
        {
            short8 kf0 = *(const short8*)kp0;  kp0 += kadv;
            short8 kf1 = *(const short8*)kp1;  kp1 += kadv;
            f32x4 s0 = __builtin_amdgcn_mfma_f32_16x16x32_bf16(kf0, qf, z, 0, 0, 0);
            f32x4 s1 = __builtin_amdgcn_mfma_f32_16x16x32_bf16(kf1, qf, z, 0, 0, 0);
            uint2 w0, w1;
            w0.x = cvtpk(hexp2(s0[0]), hexp2(s0[1]));
            w0.y = cvtpk(hexp2(s0[2]), hexp2(s0[3]));
            w1.x = cvtpk(hexp2(s1[0]), hexp2(s1[1]));
            w1.y = cvtpk(hexp2(s1[2]), hexp2(s1[3]));
            *(uint2*)&P_lds[w][0][c][4 * g]      = w0;
            *(uint2*)&P_lds[w][0][c][16 + 4 * g] = w1;
            short8 pf = *(const short8*)&P_lds[w][0][c][8 * g];
            short8 vf = *(const short8*)vp;  vp += vadv;
            acc = __builtin_amdgcn_mfma_f32_16x16x32_bf16(pf, vf, acc, 0, 0, 0);
        }
        // ---- keys kt+32 .. kt+63  (P buffer 1)
        {
            short8 kf0 = *(const short8*)kp0;  kp0 += kadv;
            short8 kf1 = *(const short8*)kp1;  kp1 += kadv;
            f32x4 s0 = __builtin_amdgcn_mfma_f32_16x16x32_bf16(kf0, qf, z, 0, 0, 0);
            f32x4 s1 = __builtin_amdgcn_mfma_f32_16x16x32_bf16(kf1, qf, z, 0, 0, 0);
            uint2 w0, w1;
            w0.x = cvtpk(hexp2(s0[0]), hexp2(s0[1]));
            w0.y = cvtpk(hexp2(s0[2]), hexp2(s0[3]));
            w1.x = cvtpk(hexp2(s1[0]), hexp2(s1[1]));
            w1.y = cvtpk(hexp2(s1[2]), hexp2(s1[3]));
            *(uint2*)&P_lds[w][1][c][4 * g]      = w0;
            *(uint2*)&P_lds[w][1][c][16 + 4 * g] = w1;
            short8 pf = *(const short8*)&P_lds[w][1][c][8 * g];
            short8 vf = *(const short8*)vp;  vp += vadv;
            acc = __builtin_amdgcn_mfma_f32_16x16x32_bf16(pf, vf, acc, 0, 0, 0);
        }
    }

    // L for rows 4g+r lives in lane (c==8, same g), reg r
    float L[4];
    #pragma unroll
    for (int r = 0; r < 4; r++) L[r] = __shfl(acc[r], (lane & 48) | 8);

    if (c < 8) {
        const int b = bh >> 7, h = bh & (Hv - 1);
        #pragma unroll
        for (int r = 0; r < 4; r++) {
            const int q = q0 + 4 * g + r;
            ctx[((size_t)(b * Sv + q)) * Ev + h * DKv + c] = f2b(acc[r] / L[r]);
        }
    }
}

// ---------------------------------------------------------------------------
extern "C" void kernel_launch(void* const* d_in, const int* in_sizes, int n_in,
                              void* d_out, int out_size, void* d_ws, size_t ws_size,
                              hipStream_t stream)
{
    const float* x   = (const float*)d_in[0];
    const float* Wq  = (const float*)d_in[1];
    const float* bq  = (const float*)d_in[2];
    // d_in[3..6] = Wk, bk, Wv, bv -- dead in the reference math.
    const float* phi = (const float*)d_in[7];
    const float* Wo  = (const float*)d_in[8];
    const float* bo  = (const float*)d_in[9];
    float* out = (float*)d_out;

    char* ws = (char*)d_ws;
    short* xb  = (short*)ws;                       // [M,E] bf16, 4 MB
    short* ctx = xb;                               // alias: written after xb's last read
    short* om  = (short*)(ws + (4 << 20));         // [B,H,S,DK] bf16 (*SQC), 4 MB
    short* Wqb = (short*)(ws + (8 << 20));         // [E,E] bf16, 2 MB
    short* Wob = (short*)(ws + (10 << 20));        // [E,E] bf16 (*ISQC), 2 MB

    cvt_all<<<dim3(2048), 256, 0, stream>>>(x, Wq, Wo, xb, Wqb, Wob);

    gemm_bf16<0><<<dim3(512), 256, 0, stream>>>(xb, Wqb, bq, phi, (void*)om);
    attn_mfma<<<dim3(Bv * Hv, Sv / 64), 256, 0, stream>>>(om, ctx);
    gemm_bf16<1><<<dim3(512), 256, 0, stream>>>(ctx, Wob, bo, nullptr, (void*)out);
}